// Round 1
// baseline (170.364 us; speedup 1.0000x reference)
//
#include <hip/hip_runtime.h>
#include <hip/hip_bf16.h>

#define KK 64
#define FF 128

__device__ __forceinline__ float sigmoidf_(float v) {
    return 1.0f / (1.0f + __expf(-v));
}

// round-to-nearest-even f32 -> bf16 (inputs here are finite, no NaN handling needed)
__device__ __forceinline__ unsigned short f2bf(float f) {
    unsigned int u;
    __builtin_memcpy(&u, &f, 4);
    unsigned int r = (u + 0x7FFFu + ((u >> 16) & 1u)) >> 16;
    return (unsigned short)r;
}

__device__ __forceinline__ float bflo(unsigned int u) {
    unsigned int v = u << 16;
    float f;
    __builtin_memcpy(&f, &v, 4);
    return f;
}
__device__ __forceinline__ float bfhi(unsigned int u) {
    unsigned int v = u & 0xFFFF0000u;
    float f;
    __builtin_memcpy(&f, &v, 4);
    return f;
}

// zero the accumulators (G 64x64 + 2 scalars) each launch
__global__ void k_init(float* __restrict__ G, float* __restrict__ scal) {
    int i = blockIdx.x * blockDim.x + threadIdx.x;
    if (i < KK * KK) G[i] = 0.0f;
    if (i < 2) scal[i] = 0.0f;
}

// Gram matrix G = A^T A (stored transposed; G is symmetric so it doesn't matter)
// plus optional store of A (bf16) and A*s (bf16) for the edge kernel.
__global__ __launch_bounds__(256) void k_gram(const float* __restrict__ logits,
                                              const float* __restrict__ s,
                                              float* __restrict__ G,
                                              unsigned short* __restrict__ Ab,
                                              unsigned short* __restrict__ Asb,
                                              int nNodes, int doStore) {
    __shared__ float rows[4][KK];
    __shared__ float sG[KK * KK];
    __shared__ float sv[KK];
    if (threadIdx.x < KK) sv[threadIdx.x] = s[threadIdx.x];
    for (int i = threadIdx.x; i < KK * KK; i += 256) sG[i] = 0.0f;

    int lane = threadIdx.x & 63;
    int wave = threadIdx.x >> 6;
    int gw = blockIdx.x * 4 + wave;
    int nw = gridDim.x * 4;
    int nIter = (nNodes + nw - 1) / nw;

    float acc[KK];
#pragma unroll
    for (int l = 0; l < KK; ++l) acc[l] = 0.0f;
    __syncthreads();

    for (int it = 0; it < nIter; ++it) {
        int n = gw + it * nw;
        float a = 0.0f;
        if (n < nNodes) {
            a = sigmoidf_(logits[(size_t)n * KK + lane]);
            if (doStore) {
                Ab[(size_t)n * KK + lane] = f2bf(a);
                Asb[(size_t)n * KK + lane] = f2bf(a * sv[lane]);
            }
        }
        __syncthreads();               // previous iteration's reads complete
        rows[wave][lane] = a;
        __syncthreads();               // writes visible to whole wave
        const float4* r4 = (const float4*)(&rows[wave][0]);
#pragma unroll
        for (int j = 0; j < KK / 4; ++j) {
            float4 v = r4[j];
            acc[4 * j + 0] += a * v.x;
            acc[4 * j + 1] += a * v.y;
            acc[4 * j + 2] += a * v.z;
            acc[4 * j + 3] += a * v.w;
        }
    }
    // combine 4 waves into LDS; layout sG[l*KK + lane] is conflict-free (bank = lane%32)
#pragma unroll
    for (int l = 0; l < KK; ++l)
        atomicAdd(&sG[l * KK + lane], acc[l]);
    __syncthreads();
    for (int i = threadIdx.x; i < KK * KK; i += 256)
        atomicAdd(&G[i], sG[i]);
}

// feature reconstruction loss: sum over (n,f) of (x[n,f] - sum_k A[n,k]*s_k*fm[k,f])^2
// each thread owns column f, keeps s_k*fm[k,f] in 64 registers.
__global__ __launch_bounds__(128) void k_feat(const float* __restrict__ logits,
                                              const float* __restrict__ x,
                                              const float* __restrict__ s,
                                              const float* __restrict__ fm,
                                              float* __restrict__ out_accum,
                                              int nNodes) {
    __shared__ float asrow[KK];
    int f = threadIdx.x; // 0..127
    float fmr[KK];
#pragma unroll
    for (int k = 0; k < KK; ++k) fmr[k] = fm[k * FF + f] * s[k];

    float acc = 0.0f;
    int nIter = (nNodes + gridDim.x - 1) / gridDim.x;
    for (int it = 0; it < nIter; ++it) {
        int n = blockIdx.x + it * gridDim.x;
        bool valid = n < nNodes;
        __syncthreads();
        if (threadIdx.x < KK)
            asrow[threadIdx.x] = valid ? sigmoidf_(logits[(size_t)n * KK + threadIdx.x]) : 0.0f;
        __syncthreads();
        if (valid) {
            float r = -x[(size_t)n * FF + f];
            const float4* a4 = (const float4*)asrow;
#pragma unroll
            for (int j = 0; j < KK / 4; ++j) {
                float4 v = a4[j];
                r += v.x * fmr[4 * j + 0] + v.y * fmr[4 * j + 1] +
                     v.z * fmr[4 * j + 2] + v.w * fmr[4 * j + 3];
            }
            acc += r * r;
        }
    }
    // block reduce (2 waves)
    for (int off = 32; off; off >>= 1) acc += __shfl_down(acc, off, 64);
    __shared__ float wsum[2];
    if ((threadIdx.x & 63) == 0) wsum[threadIdx.x >> 6] = acc;
    __syncthreads();
    if (threadIdx.x == 0) atomicAdd(out_accum, wsum[0] + wsum[1]);
}

// local term (without the final *2): sum_e sum_k A[dst_e,k]*s_k*A[src_e,k]
template <bool PRE>
__global__ __launch_bounds__(256) void k_edge(const int* __restrict__ ei,
                                              const unsigned short* __restrict__ Ab,
                                              const unsigned short* __restrict__ Asb,
                                              const float* __restrict__ logits,
                                              const float* __restrict__ s,
                                              float* __restrict__ out_accum,
                                              int nEdges) {
    __shared__ float sv[KK];
    if (threadIdx.x < KK) sv[threadIdx.x] = s[threadIdx.x];
    __syncthreads();

    float acc = 0.0f;
    int stride = gridDim.x * blockDim.x;
    for (int e = blockIdx.x * blockDim.x + threadIdx.x; e < nEdges; e += stride) {
        int srcn = ei[e];
        int dstn = ei[nEdges + e];
        if (PRE) {
            const uint4* pa = (const uint4*)(Ab + (size_t)dstn * KK);  // A[dst]
            const uint4* pb = (const uint4*)(Asb + (size_t)srcn * KK); // (A*s)[src]
#pragma unroll
            for (int j = 0; j < 8; ++j) {
                uint4 a = pa[j];
                uint4 b = pb[j];
                acc += bflo(a.x) * bflo(b.x) + bfhi(a.x) * bfhi(b.x);
                acc += bflo(a.y) * bflo(b.y) + bfhi(a.y) * bfhi(b.y);
                acc += bflo(a.z) * bflo(b.z) + bfhi(a.z) * bfhi(b.z);
                acc += bflo(a.w) * bflo(b.w) + bfhi(a.w) * bfhi(b.w);
            }
        } else {
            const float4* pa = (const float4*)(logits + (size_t)dstn * KK);
            const float4* pb = (const float4*)(logits + (size_t)srcn * KK);
#pragma unroll
            for (int j = 0; j < KK / 4; ++j) {
                float4 a = pa[j];
                float4 b = pb[j];
                acc += sigmoidf_(a.x) * sigmoidf_(b.x) * sv[4 * j + 0];
                acc += sigmoidf_(a.y) * sigmoidf_(b.y) * sv[4 * j + 1];
                acc += sigmoidf_(a.z) * sigmoidf_(b.z) * sv[4 * j + 2];
                acc += sigmoidf_(a.w) * sigmoidf_(b.w) * sv[4 * j + 3];
            }
        }
    }
    // block reduce (4 waves)
    for (int off = 32; off; off >>= 1) acc += __shfl_down(acc, off, 64);
    __shared__ float wsum[4];
    if ((threadIdx.x & 63) == 0) wsum[threadIdx.x >> 6] = acc;
    __syncthreads();
    if (threadIdx.x == 0) atomicAdd(out_accum, wsum[0] + wsum[1] + wsum[2] + wsum[3]);
}

__global__ void k_final(const float* __restrict__ G, const float* __restrict__ s,
                        const float* __restrict__ scal, float* __restrict__ out,
                        int nNodes, int nEdges) {
    __shared__ float sv[KK];
    int t = threadIdx.x; // 256
    if (t < KK) sv[t] = s[t];
    __syncthreads();
    float acc = 0.0f;
    for (int i = t; i < KK * KK; i += 256) {
        float g = G[i];
        int k = i >> 6, l = i & 63;
        acc += g * g * sv[k] * sv[l];
    }
    for (int off = 32; off; off >>= 1) acc += __shfl_down(acc, off, 64);
    __shared__ float wsum[4];
    if ((t & 63) == 0) wsum[t >> 6] = acc;
    __syncthreads();
    if (t == 0) {
        float global_term = wsum[0] + wsum[1] + wsum[2] + wsum[3];
        float local_raw = scal[0];
        float feat = scal[1];
        float loss = (global_term - 2.0f * local_raw + (float)nEdges) / (float)nNodes +
                     0.1f * feat / (float)FF;
        out[0] = loss;
    }
}

extern "C" void kernel_launch(void* const* d_in, const int* in_sizes, int n_in,
                              void* d_out, int out_size, void* d_ws, size_t ws_size,
                              hipStream_t stream) {
    const float* x = (const float*)d_in[0];
    const int* ei = (const int*)d_in[1];
    const float* logits = (const float*)d_in[2];
    const float* s = (const float*)d_in[3];
    const float* fm = (const float*)d_in[4];
    float* out = (float*)d_out;

    int nNodes = in_sizes[0] / FF;
    int nEdges = in_sizes[1] / 2;

    float* G = (float*)d_ws;          // 4096 floats
    float* scal = G + KK * KK;        // [0]=local raw sum, [1]=feature sq sum
    char* pbase = (char*)d_ws + KK * KK * 4 + 256;
    unsigned short* Ab = (unsigned short*)pbase;
    unsigned short* Asb = Ab + (size_t)nNodes * KK;
    size_t need = (size_t)KK * KK * 4 + 256 + (size_t)nNodes * KK * 2ull * 2ull;
    bool pre = ws_size >= need;

    k_init<<<16, 256, 0, stream>>>(G, scal);
    k_gram<<<256, 256, 0, stream>>>(logits, s, G, Ab, Asb, nNodes, pre ? 1 : 0);
    k_feat<<<1024, 128, 0, stream>>>(logits, x, s, fm, scal + 1, nNodes);
    if (pre)
        k_edge<true><<<1024, 256, 0, stream>>>(ei, Ab, Asb, logits, s, scal, nEdges);
    else
        k_edge<false><<<1024, 256, 0, stream>>>(ei, Ab, Asb, logits, s, scal, nEdges);
    k_final<<<1, 256, 0, stream>>>(G, s, scal, out, nNodes, nEdges);
}

// Round 2
// 55.026 us; speedup vs baseline: 3.0961x; 3.0961x over previous
//
#include <hip/hip_runtime.h>
#include <hip/hip_bf16.h>

#define KK 64
#define FF 128
#define NCH 32   // nodes per MFMA chunk

typedef __attribute__((ext_vector_type(8))) short bf16x8;
typedef __attribute__((ext_vector_type(4))) float f32x4;

__device__ __forceinline__ float SIG(float v) { return 1.0f / (1.0f + __expf(-v)); }

// round-to-nearest-even f32 -> bf16
__device__ __forceinline__ short f2bf(float f) {
    unsigned int u; __builtin_memcpy(&u, &f, 4);
    unsigned int r = (u + 0x7FFFu + ((u >> 16) & 1u)) >> 16;
    return (short)r;
}

// ---------------------------------------------------------------------------
// Fused streaming kernel: per block accumulates
//   G = A^T A (64x64, bf16 MFMA)  -> per-block partial to Gpart
//   cross = <s (x) fm, A^T X>     -> per-block scalar
//   x2 = sum(x^2)                 -> per-block scalar
// and writes the int8 A-table (A8 = round(127*sigmoid(logits))).
// LDS tiles stored transposed: AT[k][node], XT[f][node], padded stride 40.
// ---------------------------------------------------------------------------
__global__ __launch_bounds__(256) void k_fused(
    const float* __restrict__ logits, const float* __restrict__ x,
    const float* __restrict__ s, const float* __restrict__ fm,
    float* __restrict__ Gpart, float* __restrict__ crossPart,
    float* __restrict__ x2Part, signed char* __restrict__ A8,
    int nNodes, int doQuant, int nBlk)
{
    __shared__ short AT[64 * 40];    // [k][node], stride 40 bf16 (80B) -> conflict-light
    __shared__ short XT[128 * 40];   // [f][node]
    __shared__ float sv[64];
    __shared__ float wredA[4], wredB[4];

    int tid = threadIdx.x;
    int lane = tid & 63, wv = tid >> 6;
    int b = blockIdx.x;
    if (tid < 64) sv[tid] = s[tid];
    __syncthreads();

    f32x4 gacc[4], dacc[8];
#pragma unroll
    for (int i = 0; i < 4; ++i) gacc[i] = (f32x4){0.f, 0.f, 0.f, 0.f};
#pragma unroll
    for (int i = 0; i < 8; ++i) dacc[i] = (f32x4){0.f, 0.f, 0.f, 0.f};
    float x2 = 0.f, crossAcc = 0.f;

    // staging maps: logits -> (kq = tid&15 float4-col, ndl = tid>>4 node), 2 passes
    //               x      -> (fq = tid&31 float4-col, ndx = tid>>5 node), 4 passes
    int kq = tid & 15, ndl = tid >> 4;
    int fq = tid & 31, ndx = tid >> 5;
    int r16 = lane & 15, kb8 = (lane >> 4) * 8;

    int nChunks = (nNodes + NCH - 1) / NCH;
    for (int c = b; c < nChunks; c += nBlk) {
        int nb = c * NCH;
        float av[2][4];
        float xvv[4][4];
#pragma unroll
        for (int p = 0; p < 2; ++p) {
            int n = nb + ndl + 16 * p;
            bool ok = n < nNodes;
            float4 v = ok ? *(const float4*)(logits + (size_t)n * KK + 4 * kq)
                          : make_float4(0.f, 0.f, 0.f, 0.f);
            av[p][0] = ok ? SIG(v.x) : 0.f;
            av[p][1] = ok ? SIG(v.y) : 0.f;
            av[p][2] = ok ? SIG(v.z) : 0.f;
            av[p][3] = ok ? SIG(v.w) : 0.f;
            if (doQuant && ok) {
                int q0 = (int)rintf(av[p][0] * 127.f);
                int q1 = (int)rintf(av[p][1] * 127.f);
                int q2 = (int)rintf(av[p][2] * 127.f);
                int q3 = (int)rintf(av[p][3] * 127.f);
                int packed = (q0 & 255) | ((q1 & 255) << 8) | ((q2 & 255) << 16) | (q3 << 24);
                *(int*)(A8 + (size_t)n * 64 + 4 * kq) = packed;
            }
        }
#pragma unroll
        for (int p = 0; p < 4; ++p) {
            int n = nb + ndx + 8 * p;
            bool ok = n < nNodes;
            float4 v = ok ? *(const float4*)(x + (size_t)n * FF + 4 * fq)
                          : make_float4(0.f, 0.f, 0.f, 0.f);
            xvv[p][0] = v.x; xvv[p][1] = v.y; xvv[p][2] = v.z; xvv[p][3] = v.w;
            x2 += v.x * v.x + v.y * v.y + v.z * v.z + v.w * v.w;
        }
        __syncthreads();   // previous chunk's fragment reads complete
#pragma unroll
        for (int p = 0; p < 2; ++p) {
            int n = ndl + 16 * p;
#pragma unroll
            for (int j = 0; j < 4; ++j) AT[(4 * kq + j) * 40 + n] = f2bf(av[p][j]);
        }
#pragma unroll
        for (int p = 0; p < 4; ++p) {
            int n = ndx + 8 * p;
#pragma unroll
            for (int j = 0; j < 4; ++j) XT[(4 * fq + j) * 40 + n] = f2bf(xvv[p][j]);
        }
        __syncthreads();
        // fragments: A-op rows = AT[16*wv + r16], k-slice kb8..kb8+7 (nodes)
        bf16x8 af = *(bf16x8*)&AT[(16 * wv + r16) * 40 + kb8];
#pragma unroll
        for (int t = 0; t < 4; ++t) {
            bf16x8 bg = *(bf16x8*)&AT[(16 * t + r16) * 40 + kb8];
            gacc[t] = __builtin_amdgcn_mfma_f32_16x16x32_bf16(af, bg, gacc[t], 0, 0, 0);
        }
#pragma unroll
        for (int j = 0; j < 8; ++j) {
            bf16x8 bx = *(bf16x8*)&XT[(16 * j + r16) * 40 + kb8];
            dacc[j] = __builtin_amdgcn_mfma_f32_16x16x32_bf16(af, bx, dacc[j], 0, 0, 0);
        }
    }

    // --- epilogue ---
    // G partial: C/D layout col=lane&15, row=4*(lane>>4)+reg (verified mapping)
#pragma unroll
    for (int t = 0; t < 4; ++t)
#pragma unroll
        for (int r = 0; r < 4; ++r) {
            int e = (16 * wv + 4 * (lane >> 4) + r) * 64 + 16 * t + r16;
            Gpart[(size_t)b * 4096 + e] = gacc[t][r];
        }
    // cross contract: sum D[k][f] * s[k] * fm[k][f]
#pragma unroll
    for (int j = 0; j < 8; ++j)
#pragma unroll
        for (int r = 0; r < 4; ++r) {
            int kk = 16 * wv + 4 * (lane >> 4) + r;
            int ff = 16 * j + r16;
            crossAcc += dacc[j][r] * sv[kk] * fm[kk * FF + ff];
        }
#pragma unroll
    for (int off = 32; off; off >>= 1) {
        crossAcc += __shfl_down(crossAcc, off, 64);
        x2 += __shfl_down(x2, off, 64);
    }
    if (lane == 0) { wredA[wv] = crossAcc; wredB[wv] = x2; }
    __syncthreads();
    if (tid == 0) {
        crossPart[b] = wredA[0] + wredA[1] + wredA[2] + wredA[3];
        x2Part[b]    = wredB[0] + wredB[1] + wredB[2] + wredB[3];
    }
}

// ---------------------------------------------------------------------------
// Edge kernel, int8 table: sum_e sum_k A8[dst,k]*A8[src,k]*s[k]  (scale 1/127^2 later)
// Table is 3.2MB -> fits per-XCD L2; s[k] folds in as scalar-reg floats.
// ---------------------------------------------------------------------------
__global__ __launch_bounds__(256) void k_edge_i8(
    const int* __restrict__ ei, const signed char* __restrict__ A8,
    const float* __restrict__ s, float* __restrict__ edgePart, int nEdges)
{
    float acc = 0.f;
    int stride = gridDim.x * blockDim.x;
    for (int e = blockIdx.x * blockDim.x + threadIdx.x; e < nEdges; e += stride) {
        int srcn = ei[e];
        int dstn = ei[nEdges + e];
        const int4* pa = (const int4*)(A8 + (size_t)dstn * 64);
        const int4* pb = (const int4*)(A8 + (size_t)srcn * 64);
        int4 a0 = pa[0], a1 = pa[1], a2 = pa[2], a3 = pa[3];
        int4 b0 = pb[0], b1 = pb[1], b2 = pb[2], b3 = pb[3];
#define ACC4(wa, wb, kb) { int _a = (wa), _b = (wb); \
        acc += (float)(((int)(signed char)(_a & 255)) * ((int)(signed char)(_b & 255))) * s[(kb)]; \
        acc += (float)(((int)(signed char)((_a >> 8) & 255)) * ((int)(signed char)((_b >> 8) & 255))) * s[(kb) + 1]; \
        acc += (float)(((int)(signed char)((_a >> 16) & 255)) * ((int)(signed char)((_b >> 16) & 255))) * s[(kb) + 2]; \
        acc += (float)((_a >> 24) * (_b >> 24)) * s[(kb) + 3]; }
        ACC4(a0.x, b0.x, 0)  ACC4(a0.y, b0.y, 4)  ACC4(a0.z, b0.z, 8)  ACC4(a0.w, b0.w, 12)
        ACC4(a1.x, b1.x, 16) ACC4(a1.y, b1.y, 20) ACC4(a1.z, b1.z, 24) ACC4(a1.w, b1.w, 28)
        ACC4(a2.x, b2.x, 32) ACC4(a2.y, b2.y, 36) ACC4(a2.z, b2.z, 40) ACC4(a2.w, b2.w, 44)
        ACC4(a3.x, b3.x, 48) ACC4(a3.y, b3.y, 52) ACC4(a3.z, b3.z, 56) ACC4(a3.w, b3.w, 60)
#undef ACC4
    }
#pragma unroll
    for (int off = 32; off; off >>= 1) acc += __shfl_down(acc, off, 64);
    __shared__ float wsum[4];
    if ((threadIdx.x & 63) == 0) wsum[threadIdx.x >> 6] = acc;
    __syncthreads();
    if (threadIdx.x == 0) edgePart[blockIdx.x] = wsum[0] + wsum[1] + wsum[2] + wsum[3];
}

// fallback: fp32 edge gather straight from logits (no workspace table)
__global__ __launch_bounds__(256) void k_edge_f32(
    const int* __restrict__ ei, const float* __restrict__ logits,
    const float* __restrict__ s, float* __restrict__ edgePart, int nEdges)
{
    __shared__ float sv[KK];
    if (threadIdx.x < KK) sv[threadIdx.x] = s[threadIdx.x];
    __syncthreads();
    float acc = 0.f;
    int stride = gridDim.x * blockDim.x;
    for (int e = blockIdx.x * blockDim.x + threadIdx.x; e < nEdges; e += stride) {
        int srcn = ei[e];
        int dstn = ei[nEdges + e];
        const float4* pa = (const float4*)(logits + (size_t)dstn * KK);
        const float4* pb = (const float4*)(logits + (size_t)srcn * KK);
#pragma unroll
        for (int j = 0; j < KK / 4; ++j) {
            float4 a = pa[j];
            float4 b = pb[j];
            acc += SIG(a.x) * SIG(b.x) * sv[4 * j + 0];
            acc += SIG(a.y) * SIG(b.y) * sv[4 * j + 1];
            acc += SIG(a.z) * SIG(b.z) * sv[4 * j + 2];
            acc += SIG(a.w) * SIG(b.w) * sv[4 * j + 3];
        }
    }
#pragma unroll
    for (int off = 32; off; off >>= 1) acc += __shfl_down(acc, off, 64);
    __shared__ float wsum[4];
    if ((threadIdx.x & 63) == 0) wsum[threadIdx.x >> 6] = acc;
    __syncthreads();
    if (threadIdx.x == 0) edgePart[blockIdx.x] = wsum[0] + wsum[1] + wsum[2] + wsum[3];
}

// ---------------------------------------------------------------------------
// Reduce G partials -> final G entries; per block computes partial sums of
//   gq = sum G^2 * s_k * s_l   and   fq = sum G * s_k * s_l * Q[k,l],  Q = fm fm^T
// Block b owns 16 consecutive entries e = 16b..16b+15 (same k, 16 l's).
// ---------------------------------------------------------------------------
__global__ __launch_bounds__(256) void k_reduceG(
    const float* __restrict__ Gpart, const float* __restrict__ s,
    const float* __restrict__ fm, float* __restrict__ gqPart,
    float* __restrict__ fqPart, int PJ)
{
    __shared__ float red[16][17];
    __shared__ float qred[16][17];
    __shared__ float fin[2][16];
    int b = blockIdx.x, t = threadIdx.x;
    int k = b >> 2, lbase = (b & 3) * 16;
    int eloc = t & 15, pg = t >> 4;
    int ebase = b * 16;

    float sum = 0.f;
    for (int j = 0; j < PJ; ++j) {
        int p = pg + 16 * j;
        sum += Gpart[(size_t)p * 4096 + ebase + eloc];
    }
    red[pg][eloc] = sum;

    float q = 0.f;
    int l = lbase + eloc;
#pragma unroll
    for (int fi = 0; fi < 8; ++fi) {
        int f = pg * 8 + fi;
        q += fm[k * FF + f] * fm[l * FF + f];
    }
    qred[pg][eloc] = q;
    __syncthreads();
    if (t < 16) {
        float G = 0.f, Q = 0.f;
#pragma unroll
        for (int g = 0; g < 16; ++g) { G += red[g][t]; Q += qred[g][t]; }
        int ll = lbase + t;
        float ss = s[k] * s[ll];
        fin[0][t] = G * G * ss;
        fin[1][t] = G * ss * Q;
    }
    __syncthreads();
    if (t == 0) {
        float a = 0.f, c = 0.f;
#pragma unroll
        for (int g = 0; g < 16; ++g) { a += fin[0][g]; c += fin[1][g]; }
        gqPart[b] = a;
        fqPart[b] = c;
    }
}

__global__ void k_final(
    const float* __restrict__ gqPart, const float* __restrict__ fqPart,
    const float* __restrict__ crossPart, const float* __restrict__ x2Part,
    const float* __restrict__ edgePart, float* __restrict__ out,
    int nBlk, int nNodes, int nEdges, float edgeScale)
{
    int t = threadIdx.x;
    float sgq = 0.f, sfq = 0.f, scr = 0.f, sx2 = 0.f, sed = 0.f;
    for (int i = t; i < 256; i += 256) { sgq += gqPart[i]; sfq += fqPart[i]; }
    for (int i = t; i < nBlk; i += 256) { scr += crossPart[i]; sx2 += x2Part[i]; }
    for (int i = t; i < 1024; i += 256) sed += edgePart[i];
#pragma unroll
    for (int off = 32; off; off >>= 1) {
        sgq += __shfl_down(sgq, off, 64);
        sfq += __shfl_down(sfq, off, 64);
        scr += __shfl_down(scr, off, 64);
        sx2 += __shfl_down(sx2, off, 64);
        sed += __shfl_down(sed, off, 64);
    }
    __shared__ float wr[4][5];
    int wv = t >> 6;
    if ((t & 63) == 0) {
        wr[wv][0] = sgq; wr[wv][1] = sfq; wr[wv][2] = scr; wr[wv][3] = sx2; wr[wv][4] = sed;
    }
    __syncthreads();
    if (t == 0) {
        float gq = 0.f, fq = 0.f, cr = 0.f, x2 = 0.f, ed = 0.f;
#pragma unroll
        for (int g = 0; g < 4; ++g) {
            gq += wr[g][0]; fq += wr[g][1]; cr += wr[g][2]; x2 += wr[g][3]; ed += wr[g][4];
        }
        float local = ed * edgeScale;
        float feat = x2 - 2.f * cr + fq;
        out[0] = (gq - 2.f * local + (float)nEdges) / (float)nNodes + 0.1f * feat / (float)FF;
    }
}

extern "C" void kernel_launch(void* const* d_in, const int* in_sizes, int n_in,
                              void* d_out, int out_size, void* d_ws, size_t ws_size,
                              hipStream_t stream) {
    const float* x = (const float*)d_in[0];
    const int* ei = (const int*)d_in[1];
    const float* logits = (const float*)d_in[2];
    const float* s = (const float*)d_in[3];
    const float* fm = (const float*)d_in[4];
    float* out = (float*)d_out;

    int nNodes = in_sizes[0] / FF;
    int nEdges = in_sizes[1] / 2;

    auto plan = [&](int nBlk, bool quant, size_t& need, size_t* o) {
        size_t off = 0;
        o[0] = off; off += (size_t)nBlk * 4096 * 4;   // Gpart
        o[1] = off; off += (size_t)nBlk * 4;          // crossPart
        o[2] = off; off += (size_t)nBlk * 4;          // x2Part
        o[3] = off; off += 1024 * 4;                  // edgePart
        o[4] = off; off += 256 * 4;                   // gqPart
        o[5] = off; off += 256 * 4;                   // fqPart
        off = (off + 63) & ~(size_t)63;
        o[6] = off; if (quant) off += (size_t)nNodes * 64; // A8 table
        need = off;
    };
    size_t oA[7], oB[7], needA, needB;
    plan(512, true, needA, oA);
    plan(128, false, needB, oB);
    bool tierA = ws_size >= needA;
    int nBlk = tierA ? 512 : 128;
    const size_t* o = tierA ? oA : oB;
    char* w = (char*)d_ws;
    float* Gpart = (float*)(w + o[0]);
    float* crossPart = (float*)(w + o[1]);
    float* x2Part = (float*)(w + o[2]);
    float* edgePart = (float*)(w + o[3]);
    float* gqPart = (float*)(w + o[4]);
    float* fqPart = (float*)(w + o[5]);
    signed char* A8 = (signed char*)(w + o[6]);

    k_fused<<<nBlk, 256, 0, stream>>>(logits, x, s, fm, Gpart, crossPart, x2Part,
                                      A8, nNodes, tierA ? 1 : 0, nBlk);
    if (tierA)
        k_edge_i8<<<1024, 256, 0, stream>>>(ei, A8, s, edgePart, nEdges);
    else
        k_edge_f32<<<1024, 256, 0, stream>>>(ei, logits, s, edgePart, nEdges);
    k_reduceG<<<256, 256, 0, stream>>>(Gpart, s, fm, gqPart, fqPart, nBlk / 16);
    k_final<<<1, 256, 0, stream>>>(gqPart, fqPart, crossPart, x2Part, edgePart, out,
                                   nBlk, nNodes, nEdges, tierA ? (1.0f / 16129.0f) : 1.0f);
}